// Round 4
// baseline (961.752 us; speedup 1.0000x reference)
//
#include <hip/hip_runtime.h>

#define BB 8
#define SS 128
#define NN 64
#define DKK 256
#define HH 8
#define DHH 32
#define OUT0_ELEMS 16777216   // B*S*N*DK
// weights elems: B*H*S*N*N = 33554432

typedef unsigned short u16;
typedef __attribute__((ext_vector_type(8))) short short8;   // 8 bf16 (4 VGPRs)
typedef __attribute__((ext_vector_type(4))) float f32x4;    // MFMA C/D frag

#define WS_WT 1049088ull   // flag + WT hi/lo

__device__ __forceinline__ float bf2f(u16 u) {
    union { unsigned int ui; float f; } c;
    c.ui = ((unsigned int)u) << 16;
    return c.f;
}
// Bit-trick RNE f32->bf16 (kept for output packing paths).
__device__ __forceinline__ u16 f2bf(float f) {
    union { float f; unsigned int u; } c;
    c.f = f;
    unsigned int u = c.u;
    return (u16)((u + 0x7fffu + ((u >> 16) & 1u)) >> 16);
}
// Compiler-visible RNE conversion: lowers to v_cvt_pk_bf16_f32 when paired.
// Identical rounding to f2bf for finite inputs.
__device__ __forceinline__ u16 f2bf_hw(float f) {
    union { __bf16 b; u16 u; } c;
    c.b = (__bf16)f;
    return c.u;
}

// Skewed row offset for 36-float rows (+4 floats every 16 rows): breaks the
// 576-dword (bank-identical) aliasing between qq row-groups in scores/PV.
__device__ __forceinline__ int ro(int m) { return m * 36 + ((m >> 4) << 2); }

// Detect input dtype: flag=1 => f32 mode.
__global__ void k_detect(const u16* __restrict__ w, int* __restrict__ flag) {
    __shared__ int cnt;
    if (threadIdx.x == 0) cnt = 0;
    __syncthreads();
    int bad = 0;
    for (int i = threadIdx.x; i < 8192; i += 256) {
        float v = bf2f(w[i]);
        if (!(fabsf(v) <= 1e3f)) bad++;
    }
    if (bad) atomicAdd(&cnt, bad);
    __syncthreads();
    if (threadIdx.x == 0) flag[0] = (cnt > 64) ? 1 : 0;
}

// Transpose the 4 weight matrices into ws as bf16 WT[n][k] (hi always; lo
// residual only in f32 mode).
__global__ void k_wt(const void* __restrict__ w0, const void* __restrict__ w1,
                     const void* __restrict__ w2, const void* __restrict__ w3,
                     void* __restrict__ ws, const int* __restrict__ flag) {
    const int f32m = flag[0];
    const int p = blockIdx.x >> 6;
    const int chunk = blockIdx.x & 63;
    const void* W = (p == 0) ? w0 : (p == 1) ? w1 : (p == 2) ? w2 : w3;
    u16* hi = (u16*)((char*)ws + 512) + (size_t)p * 65536;
    u16* lo = hi + 4 * 65536;
#pragma unroll
    for (int ii = 0; ii < 4; ++ii) {
        int o = chunk * 1024 + ii * 256 + threadIdx.x;   // o = n*256 + k
        int n = o >> 8, k = o & 255;
        if (f32m) {
            float x = ((const float*)W)[k * 256 + n];
            u16 h = f2bf(x);
            hi[o] = h;
            lo[o] = f2bf(x - bf2f(h));
        } else {
            hi[o] = ((const u16*)W)[k * 256 + n];
        }
    }
}

// ---------------------------------------------------------------------------
// MFMA attention: one block per (b,s,h), 4 waves; wave w owns agent rows
// [16w,16w+16). F32 path: all 16 A-float4 loads hoisted ahead of the
// split+MFMA loop (deep load queue), hi/lo split via hw cvt (v_cvt_pk).
// ---------------------------------------------------------------------------
template <bool F32>
__global__ __launch_bounds__(256) void k_attn_mfma(
    const void* __restrict__ qv, const void* __restrict__ kv, const void* __restrict__ vv,
    const void* __restrict__ bQv, const void* __restrict__ bKv, const void* __restrict__ bVv,
    const void* __restrict__ ws, void* __restrict__ outv, const int* __restrict__ flag)
{
    if ((flag[0] != 0) != F32) return;

    __shared__ float sQ[2320], sK[2320], sV[2320];

    const int t = threadIdx.x;
    const int wv_ = t >> 6;          // wave id = M-tile
    const int lane = t & 63;
    const int li = lane & 15;        // A row-in-tile / B,C col-in-tile
    const int lg = lane >> 4;        // K-subgroup / C row-group
    const int bs = blockIdx.x >> 3;
    const int h = blockIdx.x & 7;
    const int b = bs >> 7;
    const int s = bs & 127;

    const u16* wt = (const u16*)((const char*)ws + 512);

    for (int p = 0; p < 3; ++p) {
        const void* Xp = (p == 0) ? qv : (p == 1) ? kv : vv;
        const void* bp = (p == 0) ? bQv : (p == 1) ? bKv : bVv;
        float bias0, bias1;
        if constexpr (F32) {
            bias0 = ((const float*)bp)[h * 32 + li];
            bias1 = ((const float*)bp)[h * 32 + 16 + li];
        } else {
            bias0 = bf2f(((const u16*)bp)[h * 32 + li]);
            bias1 = bf2f(((const u16*)bp)[h * 32 + 16 + li]);
        }
        f32x4 c0 = {bias0, bias0, bias0, bias0};
        f32x4 c1 = {bias1, bias1, bias1, bias1};
        const u16* wtp = wt + (size_t)p * 65536;
        const u16* wtl = wtp + 4 * 65536;
        const size_t arow = ((size_t)bs * 64 + wv_ * 16 + li) * 256;

        if constexpr (F32) {
            // --- hoisted A loads: 16 independent float4 loads, batched ---
            float4 X0[8], X1[8];
            const float* xp0 = (const float*)Xp + arow + lg * 8;
#pragma unroll
            for (int ks = 0; ks < 8; ++ks) {
                X0[ks] = *(const float4*)(xp0 + ks * 32);
                X1[ks] = *(const float4*)(xp0 + ks * 32 + 4);
            }
#pragma unroll
            for (int ks = 0; ks < 8; ++ks) {
                const int kof = ks * 32 + lg * 8;
                float x8[8] = {X0[ks].x, X0[ks].y, X0[ks].z, X0[ks].w,
                               X1[ks].x, X1[ks].y, X1[ks].z, X1[ks].w};
                short8 ah, al;
#pragma unroll
                for (int j = 0; j < 8; ++j) {
                    u16 hh = f2bf_hw(x8[j]);
                    ah[j] = (short)hh;
                    al[j] = (short)f2bf_hw(x8[j] - bf2f(hh));
                }
                short8 b0 = *(const short8*)(wtp + (size_t)(h * 32 + li) * 256 + kof);
                short8 b1 = *(const short8*)(wtp + (size_t)(h * 32 + 16 + li) * 256 + kof);
                short8 l0 = *(const short8*)(wtl + (size_t)(h * 32 + li) * 256 + kof);
                short8 l1 = *(const short8*)(wtl + (size_t)(h * 32 + 16 + li) * 256 + kof);
                c0 = __builtin_amdgcn_mfma_f32_16x16x32_bf16(ah, b0, c0, 0, 0, 0);
                c1 = __builtin_amdgcn_mfma_f32_16x16x32_bf16(ah, b1, c1, 0, 0, 0);
                c0 = __builtin_amdgcn_mfma_f32_16x16x32_bf16(ah, l0, c0, 0, 0, 0);
                c0 = __builtin_amdgcn_mfma_f32_16x16x32_bf16(al, b0, c0, 0, 0, 0);
                c1 = __builtin_amdgcn_mfma_f32_16x16x32_bf16(ah, l1, c1, 0, 0, 0);
                c1 = __builtin_amdgcn_mfma_f32_16x16x32_bf16(al, b1, c1, 0, 0, 0);
            }
        } else {
#pragma unroll
            for (int ks = 0; ks < 8; ++ks) {
                const int kof = ks * 32 + lg * 8;
                short8 ah = *(const short8*)((const u16*)Xp + arow + kof);
                short8 b0 = *(const short8*)(wtp + (size_t)(h * 32 + li) * 256 + kof);
                short8 b1 = *(const short8*)(wtp + (size_t)(h * 32 + 16 + li) * 256 + kof);
                c0 = __builtin_amdgcn_mfma_f32_16x16x32_bf16(ah, b0, c0, 0, 0, 0);
                c1 = __builtin_amdgcn_mfma_f32_16x16x32_bf16(ah, b1, c1, 0, 0, 0);
            }
        }

        float* dst = (p == 0) ? sQ : (p == 1) ? sK : sV;
        const int row0 = wv_ * 16 + lg * 4;
#pragma unroll
        for (int r = 0; r < 4; ++r) {
            int o = ro(row0 + r);
            dst[o + li] = c0[r];
            dst[o + 16 + li] = c1[r];
        }
    }
    __syncthreads();

    // ---- scores + softmax; thread (n,qq) owns m = qq*16 .. qq*16+15 ----
    const int n = t >> 2;
    const int qq = t & 3;
    float qr[32];
#pragma unroll
    for (int j = 0; j < 8; ++j) {
        float4 f = *(const float4*)&sQ[ro(n) + j * 4];
        qr[j * 4 + 0] = f.x; qr[j * 4 + 1] = f.y;
        qr[j * 4 + 2] = f.z; qr[j * 4 + 3] = f.w;
    }
    const float scale = 0.17677669529663687f;  // 1/sqrt(32)
    float sc[16];
#pragma unroll
    for (int i = 0; i < 16; ++i) {
        int m = qq * 16 + i;
        float d = 0.f;
        const float* kr = &sK[ro(m)];
#pragma unroll
        for (int j = 0; j < 8; ++j) {
            float4 f = *(const float4*)(kr + j * 4);
            d += qr[j * 4 + 0] * f.x + qr[j * 4 + 1] * f.y +
                 qr[j * 4 + 2] * f.z + qr[j * 4 + 3] * f.w;
        }
        sc[i] = d * scale;
    }
    float mx = sc[0];
#pragma unroll
    for (int i = 1; i < 16; ++i) mx = fmaxf(mx, sc[i]);
    mx = fmaxf(mx, __shfl_xor(mx, 1));
    mx = fmaxf(mx, __shfl_xor(mx, 2));
    float sum = 0.f;
#pragma unroll
    for (int i = 0; i < 16; ++i) { sc[i] = __expf(sc[i] - mx); sum += sc[i]; }
    sum += __shfl_xor(sum, 1);
    sum += __shfl_xor(sum, 2);
    const float inv = 1.0f / sum;
#pragma unroll
    for (int i = 0; i < 16; ++i) sc[i] *= inv;

    // weights out
    {
        size_t wbase = ((((size_t)b * HH + h) * SS + s) * NN + n) * NN + (size_t)qq * 16;
        if constexpr (F32) {
            float* wf = (float*)outv + (size_t)OUT0_ELEMS + wbase;
#pragma unroll
            for (int g = 0; g < 4; ++g) {
                float4 f; f.x = sc[g*4]; f.y = sc[g*4+1]; f.z = sc[g*4+2]; f.w = sc[g*4+3];
                *(float4*)(wf + g * 4) = f;
            }
        } else {
            u16* wo = (u16*)outv + (size_t)OUT0_ELEMS + wbase;
            union { u16 u[16]; uint4 v[2]; } wb;
#pragma unroll
            for (int i = 0; i < 16; ++i) wb.u[i] = f2bf(sc[i]);
            *(uint4*)wo = wb.v[0];
            *(uint4*)(wo + 8) = wb.v[1];
        }
    }

    // ---- P @ V ----
    float ao[32];
#pragma unroll
    for (int d = 0; d < 32; ++d) ao[d] = 0.f;
#pragma unroll
    for (int i = 0; i < 16; ++i) {
        int m = qq * 16 + i;
        float w = sc[i];
        const float* vr = &sV[ro(m)];
#pragma unroll
        for (int j = 0; j < 8; ++j) {
            float4 f = *(const float4*)(vr + j * 4);
            ao[j * 4 + 0] += w * f.x; ao[j * 4 + 1] += w * f.y;
            ao[j * 4 + 2] += w * f.z; ao[j * 4 + 3] += w * f.w;
        }
    }
#pragma unroll
    for (int d = 0; d < 32; ++d) {
        ao[d] += __shfl_xor(ao[d], 1);
        ao[d] += __shfl_xor(ao[d], 2);
    }
    {
        size_t abase = ((size_t)bs * NN + n) * DKK + h * DHH + (size_t)qq * 8;
        if constexpr (F32) {
            float* af = (float*)outv + abase;
            float4 f0, f1;
            f0.x = ao[qq*8+0]; f0.y = ao[qq*8+1]; f0.z = ao[qq*8+2]; f0.w = ao[qq*8+3];
            f1.x = ao[qq*8+4]; f1.y = ao[qq*8+5]; f1.z = ao[qq*8+6]; f1.w = ao[qq*8+7];
            *(float4*)af = f0;
            *(float4*)(af + 4) = f1;
        } else {
            union { u16 u[8]; uint4 v; } ob;
#pragma unroll
            for (int u = 0; u < 8; ++u) ob.u[u] = f2bf(ao[qq * 8 + u]);
            *(uint4*)((u16*)outv + abase) = ob.v;
        }
    }
}

// ---------------------------------------------------------------------------
// MFMA out-projection: one block per (b,s), 4 waves. attn rows pre-loaded to
// registers (bf16, matching old rounding) so the in-place write is hazard-free.
// F32 path: 16 loads hoisted, conversion via hw cvt.
// ---------------------------------------------------------------------------
template <bool F32>
__global__ __launch_bounds__(256) void k_outproj_mfma(
    const void* __restrict__ ws, const void* __restrict__ bOv,
    void* __restrict__ outv, const int* __restrict__ flag)
{
    if ((flag[0] != 0) != F32) return;

    const int t = threadIdx.x;
    const int wv_ = t >> 6, lane = t & 63, li = lane & 15, lg = lane >> 4;
    const size_t base = (size_t)blockIdx.x * (NN * DKK);
    const u16* wt = (const u16*)((const char*)ws + 512) + (size_t)3 * 65536;
    const u16* wtl = wt + 4 * 65536;

    short8 a[8];
    const size_t arow = base + (size_t)(wv_ * 16 + li) * 256;
    if constexpr (F32) {
        float4 X0[8], X1[8];
        const float* xp0 = (const float*)outv + arow + lg * 8;
#pragma unroll
        for (int ks = 0; ks < 8; ++ks) {
            X0[ks] = *(const float4*)(xp0 + ks * 32);
            X1[ks] = *(const float4*)(xp0 + ks * 32 + 4);
        }
#pragma unroll
        for (int ks = 0; ks < 8; ++ks) {
            float x8[8] = {X0[ks].x, X0[ks].y, X0[ks].z, X0[ks].w,
                           X1[ks].x, X1[ks].y, X1[ks].z, X1[ks].w};
#pragma unroll
            for (int j = 0; j < 8; ++j) a[ks][j] = (short)f2bf_hw(x8[j]);
        }
    } else {
#pragma unroll
        for (int ks = 0; ks < 8; ++ks) {
            const int kof = ks * 32 + lg * 8;
            a[ks] = *(const short8*)((const u16*)outv + arow + kof);
        }
    }

    for (int nt = 0; nt < 16; ++nt) {
        const int col = nt * 16 + li;
        float bv;
        if constexpr (F32) bv = ((const float*)bOv)[col];
        else               bv = bf2f(((const u16*)bOv)[col]);
        f32x4 c = {bv, bv, bv, bv};
#pragma unroll
        for (int ks = 0; ks < 8; ++ks) {
            const int kof = ks * 32 + lg * 8;
            short8 bh = *(const short8*)(wt + (size_t)col * 256 + kof);
            c = __builtin_amdgcn_mfma_f32_16x16x32_bf16(a[ks], bh, c, 0, 0, 0);
            if constexpr (F32) {
                short8 bl = *(const short8*)(wtl + (size_t)col * 256 + kof);
                c = __builtin_amdgcn_mfma_f32_16x16x32_bf16(a[ks], bl, c, 0, 0, 0);
            }
        }
#pragma unroll
        for (int r = 0; r < 4; ++r) {
            size_t off = base + (size_t)(wv_ * 16 + lg * 4 + r) * 256 + col;
            if constexpr (F32) ((float*)outv)[off] = c[r];
            else               ((u16*)outv)[off] = f2bf(c[r]);
        }
    }
}

// ===========================================================================
// Fallback path (original VALU kernels) — used only if workspace is tiny.
// ===========================================================================
template <bool F32>
__global__ __launch_bounds__(256) void k_attn(
    const void* __restrict__ qv, const void* __restrict__ kv, const void* __restrict__ vv,
    const void* __restrict__ WQv, const void* __restrict__ bQv,
    const void* __restrict__ WKv, const void* __restrict__ bKv,
    const void* __restrict__ WVv, const void* __restrict__ bVv,
    void* __restrict__ outv, const int* __restrict__ flag)
{
    if ((flag[0] != 0) != F32) return;

    __shared__ __align__(16) char smem[60416];
    float (*sQ)[36] = (float (*)[36])(smem + 33792);
    float (*sK)[36] = (float (*)[36])(smem + 33792 + 9216);
    float (*sV)[32] = (float (*)[32])(smem + 33792 + 18432);

    const int t  = threadIdx.x;
    const int bs = blockIdx.x >> 3;
    const int h  = blockIdx.x & 7;
    const int b  = bs >> 7;
    const int s  = bs & 127;
    const int n  = t >> 2;
    const int qq = t & 3;
    const int colbase = h * DHH + qq * 8;
    const size_t xoff = (size_t)bs * (NN * DKK);

    for (int p = 0; p < 3; ++p) {
        const void* Xp = (p == 0) ? qv : (p == 1) ? kv : vv;
        const void* Wp_ = (p == 0) ? WQv : (p == 1) ? WKv : WVv;
        const void* bp_ = (p == 0) ? bQv : (p == 1) ? bKv : bVv;
        float acc[8];

        if constexpr (F32) {
            const float* bb = (const float*)bp_;
#pragma unroll
            for (int u = 0; u < 8; ++u) acc[u] = bb[colbase + u];
            const float* X = (const float*)Xp + xoff;
            const float* W = (const float*)Wp_ + colbase;
            float (*xsf)[132] = (float (*)[132])smem;
            for (int half = 0; half < 2; ++half) {
                __syncthreads();
#pragma unroll
                for (int i = 0; i < 8; ++i) {
                    int idx = t + (i << 8);
                    int r = idx >> 5;
                    int c4 = (idx & 31) << 2;
                    *(float4*)&xsf[r][c4] =
                        *(const float4*)(X + (size_t)r * DKK + (half << 7) + c4);
                }
                __syncthreads();
#pragma unroll 4
                for (int kk2 = 0; kk2 < 128; ++kk2) {
                    int kk = (half << 7) + kk2;
                    float x = xsf[n][kk2];
                    float4 w0 = *(const float4*)(W + (size_t)kk * DKK);
                    float4 w1 = *(const float4*)(W + (size_t)kk * DKK + 4);
                    acc[0] += x * w0.x; acc[1] += x * w0.y;
                    acc[2] += x * w0.z; acc[3] += x * w0.w;
                    acc[4] += x * w1.x; acc[5] += x * w1.y;
                    acc[6] += x * w1.z; acc[7] += x * w1.w;
                }
            }
        } else {
            const u16* bb = (const u16*)bp_;
#pragma unroll
            for (int u = 0; u < 8; ++u) acc[u] = bf2f(bb[colbase + u]);
            const u16* X = (const u16*)Xp + xoff;
            const u16* W = (const u16*)Wp_ + colbase;
            u16 (*xs)[264] = (u16 (*)[264])smem;
            __syncthreads();
#pragma unroll
            for (int i = 0; i < 8; ++i) {
                int idx = t + (i << 8);
                int r = idx >> 5;
                int c = (idx & 31) << 3;
                *(uint4*)&xs[r][c] = ((const uint4*)X)[idx];
            }
            __syncthreads();
#pragma unroll 4
            for (int kk = 0; kk < DKK; ++kk) {
                float x = bf2f(xs[n][kk]);
                uint4 wv = *(const uint4*)(W + (size_t)kk * DKK);
                const u16* w8 = (const u16*)&wv;
                acc[0] += x * bf2f(w8[0]); acc[1] += x * bf2f(w8[1]);
                acc[2] += x * bf2f(w8[2]); acc[3] += x * bf2f(w8[3]);
                acc[4] += x * bf2f(w8[4]); acc[5] += x * bf2f(w8[5]);
                acc[6] += x * bf2f(w8[6]); acc[7] += x * bf2f(w8[7]);
            }
        }

        if (p == 0) {
#pragma unroll
            for (int u = 0; u < 8; ++u) sQ[n][qq * 8 + u] = acc[u];
        } else if (p == 1) {
#pragma unroll
            for (int u = 0; u < 8; ++u) sK[n][qq * 8 + u] = acc[u];
        } else {
#pragma unroll
            for (int u = 0; u < 8; ++u) sV[n][qq * 8 + u] = acc[u];
        }
    }
    __syncthreads();

    float qr[32];
#pragma unroll
    for (int j = 0; j < 8; ++j) {
        float4 f = *(const float4*)&sQ[n][j * 4];
        qr[j * 4 + 0] = f.x; qr[j * 4 + 1] = f.y;
        qr[j * 4 + 2] = f.z; qr[j * 4 + 3] = f.w;
    }
    const float scale = 0.17677669529663687f;
    float sc[16];
#pragma unroll
    for (int i = 0; i < 16; ++i) {
        int m = qq * 16 + i;
        float d = 0.f;
#pragma unroll
        for (int j = 0; j < 8; ++j) {
            float4 f = *(const float4*)&sK[m][j * 4];
            d += qr[j * 4 + 0] * f.x + qr[j * 4 + 1] * f.y +
                 qr[j * 4 + 2] * f.z + qr[j * 4 + 3] * f.w;
        }
        sc[i] = d * scale;
    }
    float mx = sc[0];
#pragma unroll
    for (int i = 1; i < 16; ++i) mx = fmaxf(mx, sc[i]);
    mx = fmaxf(mx, __shfl_xor(mx, 1));
    mx = fmaxf(mx, __shfl_xor(mx, 2));
    float sum = 0.f;
#pragma unroll
    for (int i = 0; i < 16; ++i) { sc[i] = __expf(sc[i] - mx); sum += sc[i]; }
    sum += __shfl_xor(sum, 1);
    sum += __shfl_xor(sum, 2);
    const float inv = 1.0f / sum;
#pragma unroll
    for (int i = 0; i < 16; ++i) sc[i] *= inv;

    {
        size_t wbase = ((((size_t)b * HH + h) * SS + s) * NN + n) * NN + (size_t)qq * 16;
        if constexpr (F32) {
            float* wf = (float*)outv + (size_t)OUT0_ELEMS + wbase;
#pragma unroll
            for (int g = 0; g < 4; ++g) {
                float4 f; f.x = sc[g*4]; f.y = sc[g*4+1]; f.z = sc[g*4+2]; f.w = sc[g*4+3];
                *(float4*)(wf + g * 4) = f;
            }
        } else {
            u16* wo = (u16*)outv + (size_t)OUT0_ELEMS + wbase;
            union { u16 u[16]; uint4 v[2]; } wb;
#pragma unroll
            for (int i = 0; i < 16; ++i) wb.u[i] = f2bf(sc[i]);
            *(uint4*)wo = wb.v[0];
            *(uint4*)(wo + 8) = wb.v[1];
        }
    }

    float ao[32];
#pragma unroll
    for (int d = 0; d < 32; ++d) ao[d] = 0.f;
#pragma unroll
    for (int i = 0; i < 16; ++i) {
        int m = qq * 16 + i;
        float w = sc[i];
#pragma unroll
        for (int j = 0; j < 8; ++j) {
            float4 f = *(const float4*)&sV[m][j * 4];
            ao[j * 4 + 0] += w * f.x; ao[j * 4 + 1] += w * f.y;
            ao[j * 4 + 2] += w * f.z; ao[j * 4 + 3] += w * f.w;
        }
    }
#pragma unroll
    for (int d = 0; d < 32; ++d) {
        ao[d] += __shfl_xor(ao[d], 1);
        ao[d] += __shfl_xor(ao[d], 2);
    }
    {
        size_t abase = ((size_t)bs * NN + n) * DKK + h * DHH + (size_t)qq * 8;
        if constexpr (F32) {
            float* af = (float*)outv + abase;
            float4 f0, f1;
            f0.x = ao[qq*8+0]; f0.y = ao[qq*8+1]; f0.z = ao[qq*8+2]; f0.w = ao[qq*8+3];
            f1.x = ao[qq*8+4]; f1.y = ao[qq*8+5]; f1.z = ao[qq*8+6]; f1.w = ao[qq*8+7];
            *(float4*)af = f0;
            *(float4*)(af + 4) = f1;
        } else {
            union { u16 u[8]; uint4 v; } ob;
#pragma unroll
            for (int u = 0; u < 8; ++u) ob.u[u] = f2bf(ao[qq * 8 + u]);
            *(uint4*)((u16*)outv + abase) = ob.v;
        }
    }
}

template <bool F32>
__global__ __launch_bounds__(256) void k_outproj(
    const void* __restrict__ WOv, const void* __restrict__ bOv,
    void* __restrict__ outv, const int* __restrict__ flag)
{
    if ((flag[0] != 0) != F32) return;

    __shared__ __align__(16) u16 xs[64][264];
    const int t = threadIdx.x;
    const size_t base = (size_t)blockIdx.x * (NN * DKK);

    if constexpr (F32) {
        const float* ag = (const float*)outv + base;
#pragma unroll
        for (int i = 0; i < 16; ++i) {
            int idx = t + (i << 8);
            int r = idx >> 6;
            int c4 = (idx & 63) << 2;
            float4 f = *(const float4*)(ag + (size_t)r * DKK + c4);
            union { u16 u[4]; uint2 v; } pk;
            pk.u[0] = f2bf(f.x); pk.u[1] = f2bf(f.y);
            pk.u[2] = f2bf(f.z); pk.u[3] = f2bf(f.w);
            *(uint2*)&xs[r][c4] = pk.v;
        }
    } else {
        const u16* ag = (const u16*)outv + base;
#pragma unroll
        for (int i = 0; i < 8; ++i) {
            int idx = t + (i << 8);
            int r = idx >> 5;
            int c = (idx & 31) << 3;
            *(uint4*)&xs[r][c] = ((const uint4*)ag)[idx];
        }
    }
    __syncthreads();

    const int n = t >> 2;
    const int jj = t & 3;
    for (int cg = 0; cg < 8; ++cg) {
        const int colbase = cg * 32 + jj * 8;
        float acc[8];
        if constexpr (F32) {
            const float* bb = (const float*)bOv;
#pragma unroll
            for (int u = 0; u < 8; ++u) acc[u] = bb[colbase + u];
        } else {
            const u16* bb = (const u16*)bOv;
#pragma unroll
            for (int u = 0; u < 8; ++u) acc[u] = bf2f(bb[colbase + u]);
        }
        const u16* xr = xs[n];
        if constexpr (F32) {
            const float* W = (const float*)WOv + colbase;
#pragma unroll 4
            for (int kk = 0; kk < DKK; ++kk) {
                float x = bf2f(xr[kk]);
                float4 w0 = *(const float4*)(W + (size_t)kk * DKK);
                float4 w1 = *(const float4*)(W + (size_t)kk * DKK + 4);
                acc[0] += x * w0.x; acc[1] += x * w0.y;
                acc[2] += x * w0.z; acc[3] += x * w0.w;
                acc[4] += x * w1.x; acc[5] += x * w1.y;
                acc[6] += x * w1.z; acc[7] += x * w1.w;
            }
        } else {
            const u16* W = (const u16*)WOv + colbase;
#pragma unroll 4
            for (int kk = 0; kk < DKK; ++kk) {
                float x = bf2f(xr[kk]);
                uint4 wv = *(const uint4*)(W + (size_t)kk * DKK);
                const u16* w8 = (const u16*)&wv;
                acc[0] += x * bf2f(w8[0]); acc[1] += x * bf2f(w8[1]);
                acc[2] += x * bf2f(w8[2]); acc[3] += x * bf2f(w8[3]);
                acc[4] += x * bf2f(w8[4]); acc[5] += x * bf2f(w8[5]);
                acc[6] += x * bf2f(w8[6]); acc[7] += x * bf2f(w8[7]);
            }
        }
        if constexpr (F32) {
            float* og = (float*)outv + base + (size_t)n * DKK + colbase;
            float4 f0, f1;
            f0.x = acc[0]; f0.y = acc[1]; f0.z = acc[2]; f0.w = acc[3];
            f1.x = acc[4]; f1.y = acc[5]; f1.z = acc[6]; f1.w = acc[7];
            *(float4*)og = f0;
            *(float4*)(og + 4) = f1;
        } else {
            union { u16 u[8]; uint4 v; } ob;
#pragma unroll
            for (int u = 0; u < 8; ++u) ob.u[u] = f2bf(acc[u]);
            *(uint4*)((u16*)outv + base + (size_t)n * DKK + colbase) = ob.v;
        }
    }
}

extern "C" void kernel_launch(void* const* d_in, const int* in_sizes, int n_in,
                              void* d_out, int out_size, void* d_ws, size_t ws_size,
                              hipStream_t stream) {
    (void)in_sizes; (void)n_in; (void)out_size;
    int* flag = (int*)d_ws;

    k_detect<<<1, 256, 0, stream>>>((const u16*)d_in[3], flag);

    if (ws_size >= WS_WT) {
        k_wt<<<256, 256, 0, stream>>>(d_in[3], d_in[5], d_in[7], d_in[9], d_ws, flag);

        k_attn_mfma<false><<<BB * SS * HH, 256, 0, stream>>>(
            d_in[0], d_in[1], d_in[2], d_in[4], d_in[6], d_in[8],
            d_ws, d_out, flag);
        k_attn_mfma<true><<<BB * SS * HH, 256, 0, stream>>>(
            d_in[0], d_in[1], d_in[2], d_in[4], d_in[6], d_in[8],
            d_ws, d_out, flag);

        k_outproj_mfma<false><<<BB * SS, 256, 0, stream>>>(d_ws, d_in[10], d_out, flag);
        k_outproj_mfma<true><<<BB * SS, 256, 0, stream>>>(d_ws, d_in[10], d_out, flag);
    } else {
        k_attn<false><<<BB * SS * HH, 256, 0, stream>>>(
            d_in[0], d_in[1], d_in[2], d_in[3], d_in[4], d_in[5], d_in[6],
            d_in[7], d_in[8], d_out, flag);
        k_attn<true><<<BB * SS * HH, 256, 0, stream>>>(
            d_in[0], d_in[1], d_in[2], d_in[3], d_in[4], d_in[5], d_in[6],
            d_in[7], d_in[8], d_out, flag);

        k_outproj<false><<<BB * SS, 256, 0, stream>>>(d_in[9], d_in[10], d_out, flag);
        k_outproj<true><<<BB * SS, 256, 0, stream>>>(d_in[9], d_in[10], d_out, flag);
    }
}

// Round 5
// 952.283 us; speedup vs baseline: 1.0099x; 1.0099x over previous
//
#include <hip/hip_runtime.h>

#define BB 8
#define SS 128
#define NN 64
#define DKK 256
#define HH 8
#define DHH 32
#define OUT0_ELEMS 16777216   // B*S*N*DK
// weights elems: B*H*S*N*N = 33554432

typedef unsigned short u16;
typedef __attribute__((ext_vector_type(8))) short short8;   // 8 bf16 (4 VGPRs)
typedef __attribute__((ext_vector_type(4))) float f32x4;    // MFMA C/D frag

#define WS_WT 1049088ull   // flag + WT hi/lo

__device__ __forceinline__ float bf2f(u16 u) {
    union { unsigned int ui; float f; } c;
    c.ui = ((unsigned int)u) << 16;
    return c.f;
}
// Bit-trick RNE f32->bf16 (kept for output packing paths).
__device__ __forceinline__ u16 f2bf(float f) {
    union { float f; unsigned int u; } c;
    c.f = f;
    unsigned int u = c.u;
    return (u16)((u + 0x7fffu + ((u >> 16) & 1u)) >> 16);
}
// Compiler-visible RNE conversion (lowers to v_cvt_pk_bf16_f32 when paired).
__device__ __forceinline__ u16 f2bf_hw(float f) {
    union { __bf16 b; u16 u; } c;
    c.b = (__bf16)f;
    return c.u;
}

// Skewed row offset for 36-float rows (+4 floats every 16 rows): breaks the
// 576-dword (bank-identical) aliasing between qq row-groups in scores/PV.
__device__ __forceinline__ int ro(int m) { return m * 36 + ((m >> 4) << 2); }

// Detect input dtype: flag=1 => f32 mode.
__global__ void k_detect(const u16* __restrict__ w, int* __restrict__ flag) {
    __shared__ int cnt;
    if (threadIdx.x == 0) cnt = 0;
    __syncthreads();
    int bad = 0;
    for (int i = threadIdx.x; i < 8192; i += 256) {
        float v = bf2f(w[i]);
        if (!(fabsf(v) <= 1e3f)) bad++;
    }
    if (bad) atomicAdd(&cnt, bad);
    __syncthreads();
    if (threadIdx.x == 0) flag[0] = (cnt > 64) ? 1 : 0;
}

// Transpose the 4 weight matrices into ws as bf16 WT[n][k] (hi always; lo
// residual only in f32 mode). Coalesced via 64x64 LDS tile transpose
// (old version read W column-major: stride-1KB dwords, ~16x sector
// over-fetch and pure latency).
// grid: 4 matrices x 16 tiles (4x4 of 64x64) = 64 blocks, 256 threads.
__global__ __launch_bounds__(256) void k_wt(
    const void* __restrict__ w0, const void* __restrict__ w1,
    const void* __restrict__ w2, const void* __restrict__ w3,
    void* __restrict__ ws, const int* __restrict__ flag) {
    const int f32m = flag[0];
    const int p = blockIdx.x >> 4;
    const int tile = blockIdx.x & 15;
    const int ko = (tile >> 2) << 6;
    const int no = (tile & 3) << 6;
    const void* W = (p == 0) ? w0 : (p == 1) ? w1 : (p == 2) ? w2 : w3;
    u16* hi = (u16*)((char*)ws + 512) + (size_t)p * 65536;
    u16* lo = hi + 4 * 65536;

    __shared__ __align__(16) char tbuf[64 * 65 * 4];
    const int t = threadIdx.x;
    const int tq = t >> 6;        // 0..3
    const int tc = t & 63;        // 0..63

    if (f32m) {
        float (*tl)[65] = (float (*)[65])tbuf;
#pragma unroll
        for (int rr = 0; rr < 16; ++rr) {
            int kk = tq + (rr << 2);
            tl[kk][tc] = ((const float*)W)[(size_t)(ko + kk) * 256 + no + tc];
        }
        __syncthreads();
#pragma unroll
        for (int rr = 0; rr < 16; ++rr) {
            int nn = tq + (rr << 2);
            float x = tl[tc][nn];
            u16 h = f2bf(x);
            size_t o = (size_t)(no + nn) * 256 + ko + tc;
            hi[o] = h;
            lo[o] = f2bf(x - bf2f(h));
        }
    } else {
        u16 (*tl)[65] = (u16 (*)[65])tbuf;
#pragma unroll
        for (int rr = 0; rr < 16; ++rr) {
            int kk = tq + (rr << 2);
            tl[kk][tc] = ((const u16*)W)[(size_t)(ko + kk) * 256 + no + tc];
        }
        __syncthreads();
#pragma unroll
        for (int rr = 0; rr < 16; ++rr) {
            int nn = tq + (rr << 2);
            hi[(size_t)(no + nn) * 256 + ko + tc] = tl[tc][nn];
        }
    }
}

// ---------------------------------------------------------------------------
// MFMA attention: one block per (b,s,h), 4 waves; wave w owns agent rows
// [16w,16w+16). XCD-aware work swizzle: all 8 head-blocks of a (b,s) share
// blockIdx%8 -> same XCD L2 serves the shared 196KB X-slab (consecutive
// blockIdx round-robins XCDs on MI355X). F32 path: 16 A-float4 loads hoisted,
// hi/lo split via hw cvt.
// ---------------------------------------------------------------------------
template <bool F32>
__global__ __launch_bounds__(256) void k_attn_mfma(
    const void* __restrict__ qv, const void* __restrict__ kv, const void* __restrict__ vv,
    const void* __restrict__ bQv, const void* __restrict__ bKv, const void* __restrict__ bVv,
    const void* __restrict__ ws, void* __restrict__ outv, const int* __restrict__ flag)
{
    if ((flag[0] != 0) != F32) return;

    __shared__ float sQ[2320], sK[2320], sV[2320];

    const int t = threadIdx.x;
    const int wv_ = t >> 6;          // wave id = M-tile
    const int lane = t & 63;
    const int li = lane & 15;        // A row-in-tile / B,C col-in-tile
    const int lg = lane >> 4;        // K-subgroup / C row-group
    // XCD swizzle: lid = (bs%8) + 8*h + 64*(bs/8)  (bijective on [0,8192))
    const int lid = blockIdx.x;
    const int bs = (lid & 7) + ((lid >> 6) << 3);
    const int h = (lid >> 3) & 7;
    const int b = bs >> 7;
    const int s = bs & 127;

    const u16* wt = (const u16*)((const char*)ws + 512);

    for (int p = 0; p < 3; ++p) {
        const void* Xp = (p == 0) ? qv : (p == 1) ? kv : vv;
        const void* bp = (p == 0) ? bQv : (p == 1) ? bKv : bVv;
        float bias0, bias1;
        if constexpr (F32) {
            bias0 = ((const float*)bp)[h * 32 + li];
            bias1 = ((const float*)bp)[h * 32 + 16 + li];
        } else {
            bias0 = bf2f(((const u16*)bp)[h * 32 + li]);
            bias1 = bf2f(((const u16*)bp)[h * 32 + 16 + li]);
        }
        f32x4 c0 = {bias0, bias0, bias0, bias0};
        f32x4 c1 = {bias1, bias1, bias1, bias1};
        const u16* wtp = wt + (size_t)p * 65536;
        const u16* wtl = wtp + 4 * 65536;
        const size_t arow = ((size_t)bs * 64 + wv_ * 16 + li) * 256;

        if constexpr (F32) {
            // --- hoisted A loads: 16 independent float4 loads, batched ---
            float4 X0[8], X1[8];
            const float* xp0 = (const float*)Xp + arow + lg * 8;
#pragma unroll
            for (int ks = 0; ks < 8; ++ks) {
                X0[ks] = *(const float4*)(xp0 + ks * 32);
                X1[ks] = *(const float4*)(xp0 + ks * 32 + 4);
            }
#pragma unroll
            for (int ks = 0; ks < 8; ++ks) {
                const int kof = ks * 32 + lg * 8;
                float x8[8] = {X0[ks].x, X0[ks].y, X0[ks].z, X0[ks].w,
                               X1[ks].x, X1[ks].y, X1[ks].z, X1[ks].w};
                short8 ah, al;
#pragma unroll
                for (int j = 0; j < 8; ++j) {
                    u16 hh = f2bf_hw(x8[j]);
                    ah[j] = (short)hh;
                    al[j] = (short)f2bf_hw(x8[j] - bf2f(hh));
                }
                short8 b0 = *(const short8*)(wtp + (size_t)(h * 32 + li) * 256 + kof);
                short8 b1 = *(const short8*)(wtp + (size_t)(h * 32 + 16 + li) * 256 + kof);
                short8 l0 = *(const short8*)(wtl + (size_t)(h * 32 + li) * 256 + kof);
                short8 l1 = *(const short8*)(wtl + (size_t)(h * 32 + 16 + li) * 256 + kof);
                c0 = __builtin_amdgcn_mfma_f32_16x16x32_bf16(ah, b0, c0, 0, 0, 0);
                c1 = __builtin_amdgcn_mfma_f32_16x16x32_bf16(ah, b1, c1, 0, 0, 0);
                c0 = __builtin_amdgcn_mfma_f32_16x16x32_bf16(ah, l0, c0, 0, 0, 0);
                c0 = __builtin_amdgcn_mfma_f32_16x16x32_bf16(al, b0, c0, 0, 0, 0);
                c1 = __builtin_amdgcn_mfma_f32_16x16x32_bf16(ah, l1, c1, 0, 0, 0);
                c1 = __builtin_amdgcn_mfma_f32_16x16x32_bf16(al, b1, c1, 0, 0, 0);
            }
        } else {
#pragma unroll
            for (int ks = 0; ks < 8; ++ks) {
                const int kof = ks * 32 + lg * 8;
                short8 ah = *(const short8*)((const u16*)Xp + arow + kof);
                short8 b0 = *(const short8*)(wtp + (size_t)(h * 32 + li) * 256 + kof);
                short8 b1 = *(const short8*)(wtp + (size_t)(h * 32 + 16 + li) * 256 + kof);
                c0 = __builtin_amdgcn_mfma_f32_16x16x32_bf16(ah, b0, c0, 0, 0, 0);
                c1 = __builtin_amdgcn_mfma_f32_16x16x32_bf16(ah, b1, c1, 0, 0, 0);
            }
        }

        float* dst = (p == 0) ? sQ : (p == 1) ? sK : sV;
        const int row0 = wv_ * 16 + lg * 4;
#pragma unroll
        for (int r = 0; r < 4; ++r) {
            int o = ro(row0 + r);
            dst[o + li] = c0[r];
            dst[o + 16 + li] = c1[r];
        }
    }
    __syncthreads();

    // ---- scores + softmax; thread (n,qq) owns m = qq*16 .. qq*16+15 ----
    const int n = t >> 2;
    const int qq = t & 3;
    float qr[32];
#pragma unroll
    for (int j = 0; j < 8; ++j) {
        float4 f = *(const float4*)&sQ[ro(n) + j * 4];
        qr[j * 4 + 0] = f.x; qr[j * 4 + 1] = f.y;
        qr[j * 4 + 2] = f.z; qr[j * 4 + 3] = f.w;
    }
    const float scale = 0.17677669529663687f;  // 1/sqrt(32)
    float sc[16];
#pragma unroll
    for (int i = 0; i < 16; ++i) {
        int m = qq * 16 + i;
        float d = 0.f;
        const float* kr = &sK[ro(m)];
#pragma unroll
        for (int j = 0; j < 8; ++j) {
            float4 f = *(const float4*)(kr + j * 4);
            d += qr[j * 4 + 0] * f.x + qr[j * 4 + 1] * f.y +
                 qr[j * 4 + 2] * f.z + qr[j * 4 + 3] * f.w;
        }
        sc[i] = d * scale;
    }
    float mx = sc[0];
#pragma unroll
    for (int i = 1; i < 16; ++i) mx = fmaxf(mx, sc[i]);
    mx = fmaxf(mx, __shfl_xor(mx, 1));
    mx = fmaxf(mx, __shfl_xor(mx, 2));
    float sum = 0.f;
#pragma unroll
    for (int i = 0; i < 16; ++i) { sc[i] = __expf(sc[i] - mx); sum += sc[i]; }
    sum += __shfl_xor(sum, 1);
    sum += __shfl_xor(sum, 2);
    const float inv = 1.0f / sum;
#pragma unroll
    for (int i = 0; i < 16; ++i) sc[i] *= inv;

    // weights out
    {
        size_t wbase = ((((size_t)b * HH + h) * SS + s) * NN + n) * NN + (size_t)qq * 16;
        if constexpr (F32) {
            float* wf = (float*)outv + (size_t)OUT0_ELEMS + wbase;
#pragma unroll
            for (int g = 0; g < 4; ++g) {
                float4 f; f.x = sc[g*4]; f.y = sc[g*4+1]; f.z = sc[g*4+2]; f.w = sc[g*4+3];
                *(float4*)(wf + g * 4) = f;
            }
        } else {
            u16* wo = (u16*)outv + (size_t)OUT0_ELEMS + wbase;
            union { u16 u[16]; uint4 v[2]; } wb;
#pragma unroll
            for (int i = 0; i < 16; ++i) wb.u[i] = f2bf(sc[i]);
            *(uint4*)wo = wb.v[0];
            *(uint4*)(wo + 8) = wb.v[1];
        }
    }

    // ---- P @ V ----
    float ao[32];
#pragma unroll
    for (int d = 0; d < 32; ++d) ao[d] = 0.f;
#pragma unroll
    for (int i = 0; i < 16; ++i) {
        int m = qq * 16 + i;
        float w = sc[i];
        const float* vr = &sV[ro(m)];
#pragma unroll
        for (int j = 0; j < 8; ++j) {
            float4 f = *(const float4*)(vr + j * 4);
            ao[j * 4 + 0] += w * f.x; ao[j * 4 + 1] += w * f.y;
            ao[j * 4 + 2] += w * f.z; ao[j * 4 + 3] += w * f.w;
        }
    }
#pragma unroll
    for (int d = 0; d < 32; ++d) {
        ao[d] += __shfl_xor(ao[d], 1);
        ao[d] += __shfl_xor(ao[d], 2);
    }
    {
        size_t abase = ((size_t)bs * NN + n) * DKK + h * DHH + (size_t)qq * 8;
        if constexpr (F32) {
            float* af = (float*)outv + abase;
            float4 f0, f1;
            f0.x = ao[qq*8+0]; f0.y = ao[qq*8+1]; f0.z = ao[qq*8+2]; f0.w = ao[qq*8+3];
            f1.x = ao[qq*8+4]; f1.y = ao[qq*8+5]; f1.z = ao[qq*8+6]; f1.w = ao[qq*8+7];
            *(float4*)af = f0;
            *(float4*)(af + 4) = f1;
        } else {
            union { u16 u[8]; uint4 v; } ob;
#pragma unroll
            for (int u = 0; u < 8; ++u) ob.u[u] = f2bf(ao[qq * 8 + u]);
            *(uint4*)((u16*)outv + abase) = ob.v;
        }
    }
}

// ---------------------------------------------------------------------------
// MFMA out-projection: one block per (b,s), 4 waves. attn rows pre-loaded to
// registers (bf16, matching old rounding) so the in-place write is hazard-free.
// ---------------------------------------------------------------------------
template <bool F32>
__global__ __launch_bounds__(256) void k_outproj_mfma(
    const void* __restrict__ ws, const void* __restrict__ bOv,
    void* __restrict__ outv, const int* __restrict__ flag)
{
    if ((flag[0] != 0) != F32) return;

    const int t = threadIdx.x;
    const int wv_ = t >> 6, lane = t & 63, li = lane & 15, lg = lane >> 4;
    const size_t base = (size_t)blockIdx.x * (NN * DKK);
    const u16* wt = (const u16*)((const char*)ws + 512) + (size_t)3 * 65536;
    const u16* wtl = wt + 4 * 65536;

    short8 a[8];
    const size_t arow = base + (size_t)(wv_ * 16 + li) * 256;
    if constexpr (F32) {
        float4 X0[8], X1[8];
        const float* xp0 = (const float*)outv + arow + lg * 8;
#pragma unroll
        for (int ks = 0; ks < 8; ++ks) {
            X0[ks] = *(const float4*)(xp0 + ks * 32);
            X1[ks] = *(const float4*)(xp0 + ks * 32 + 4);
        }
#pragma unroll
        for (int ks = 0; ks < 8; ++ks) {
            float x8[8] = {X0[ks].x, X0[ks].y, X0[ks].z, X0[ks].w,
                           X1[ks].x, X1[ks].y, X1[ks].z, X1[ks].w};
#pragma unroll
            for (int j = 0; j < 8; ++j) a[ks][j] = (short)f2bf_hw(x8[j]);
        }
    } else {
#pragma unroll
        for (int ks = 0; ks < 8; ++ks) {
            const int kof = ks * 32 + lg * 8;
            a[ks] = *(const short8*)((const u16*)outv + arow + kof);
        }
    }

    for (int nt = 0; nt < 16; ++nt) {
        const int col = nt * 16 + li;
        float bv;
        if constexpr (F32) bv = ((const float*)bOv)[col];
        else               bv = bf2f(((const u16*)bOv)[col]);
        f32x4 c = {bv, bv, bv, bv};
#pragma unroll
        for (int ks = 0; ks < 8; ++ks) {
            const int kof = ks * 32 + lg * 8;
            short8 bh = *(const short8*)(wt + (size_t)col * 256 + kof);
            c = __builtin_amdgcn_mfma_f32_16x16x32_bf16(a[ks], bh, c, 0, 0, 0);
            if constexpr (F32) {
                short8 bl = *(const short8*)(wtl + (size_t)col * 256 + kof);
                c = __builtin_amdgcn_mfma_f32_16x16x32_bf16(a[ks], bl, c, 0, 0, 0);
            }
        }
#pragma unroll
        for (int r = 0; r < 4; ++r) {
            size_t off = base + (size_t)(wv_ * 16 + lg * 4 + r) * 256 + col;
            if constexpr (F32) ((float*)outv)[off] = c[r];
            else               ((u16*)outv)[off] = f2bf(c[r]);
        }
    }
}

// ===========================================================================
// Fallback path (original VALU kernels) — used only if workspace is tiny.
// ===========================================================================
template <bool F32>
__global__ __launch_bounds__(256) void k_attn(
    const void* __restrict__ qv, const void* __restrict__ kv, const void* __restrict__ vv,
    const void* __restrict__ WQv, const void* __restrict__ bQv,
    const void* __restrict__ WKv, const void* __restrict__ bKv,
    const void* __restrict__ WVv, const void* __restrict__ bVv,
    void* __restrict__ outv, const int* __restrict__ flag)
{
    if ((flag[0] != 0) != F32) return;

    __shared__ __align__(16) char smem[60416];
    float (*sQ)[36] = (float (*)[36])(smem + 33792);
    float (*sK)[36] = (float (*)[36])(smem + 33792 + 9216);
    float (*sV)[32] = (float (*)[32])(smem + 33792 + 18432);

    const int t  = threadIdx.x;
    const int bs = blockIdx.x >> 3;
    const int h  = blockIdx.x & 7;
    const int b  = bs >> 7;
    const int s  = bs & 127;
    const int n  = t >> 2;
    const int qq = t & 3;
    const int colbase = h * DHH + qq * 8;
    const size_t xoff = (size_t)bs * (NN * DKK);

    for (int p = 0; p < 3; ++p) {
        const void* Xp = (p == 0) ? qv : (p == 1) ? kv : vv;
        const void* Wp_ = (p == 0) ? WQv : (p == 1) ? WKv : WVv;
        const void* bp_ = (p == 0) ? bQv : (p == 1) ? bKv : bVv;
        float acc[8];

        if constexpr (F32) {
            const float* bb = (const float*)bp_;
#pragma unroll
            for (int u = 0; u < 8; ++u) acc[u] = bb[colbase + u];
            const float* X = (const float*)Xp + xoff;
            const float* W = (const float*)Wp_ + colbase;
            float (*xsf)[132] = (float (*)[132])smem;
            for (int half = 0; half < 2; ++half) {
                __syncthreads();
#pragma unroll
                for (int i = 0; i < 8; ++i) {
                    int idx = t + (i << 8);
                    int r = idx >> 5;
                    int c4 = (idx & 31) << 2;
                    *(float4*)&xsf[r][c4] =
                        *(const float4*)(X + (size_t)r * DKK + (half << 7) + c4);
                }
                __syncthreads();
#pragma unroll 4
                for (int kk2 = 0; kk2 < 128; ++kk2) {
                    int kk = (half << 7) + kk2;
                    float x = xsf[n][kk2];
                    float4 w0 = *(const float4*)(W + (size_t)kk * DKK);
                    float4 w1 = *(const float4*)(W + (size_t)kk * DKK + 4);
                    acc[0] += x * w0.x; acc[1] += x * w0.y;
                    acc[2] += x * w0.z; acc[3] += x * w0.w;
                    acc[4] += x * w1.x; acc[5] += x * w1.y;
                    acc[6] += x * w1.z; acc[7] += x * w1.w;
                }
            }
        } else {
            const u16* bb = (const u16*)bp_;
#pragma unroll
            for (int u = 0; u < 8; ++u) acc[u] = bf2f(bb[colbase + u]);
            const u16* X = (const u16*)Xp + xoff;
            const u16* W = (const u16*)Wp_ + colbase;
            u16 (*xs)[264] = (u16 (*)[264])smem;
            __syncthreads();
#pragma unroll
            for (int i = 0; i < 8; ++i) {
                int idx = t + (i << 8);
                int r = idx >> 5;
                int c = (idx & 31) << 3;
                *(uint4*)&xs[r][c] = ((const uint4*)X)[idx];
            }
            __syncthreads();
#pragma unroll 4
            for (int kk = 0; kk < DKK; ++kk) {
                float x = bf2f(xs[n][kk]);
                uint4 wv = *(const uint4*)(W + (size_t)kk * DKK);
                const u16* w8 = (const u16*)&wv;
                acc[0] += x * bf2f(w8[0]); acc[1] += x * bf2f(w8[1]);
                acc[2] += x * bf2f(w8[2]); acc[3] += x * bf2f(w8[3]);
                acc[4] += x * bf2f(w8[4]); acc[5] += x * bf2f(w8[5]);
                acc[6] += x * bf2f(w8[6]); acc[7] += x * bf2f(w8[7]);
            }
        }

        if (p == 0) {
#pragma unroll
            for (int u = 0; u < 8; ++u) sQ[n][qq * 8 + u] = acc[u];
        } else if (p == 1) {
#pragma unroll
            for (int u = 0; u < 8; ++u) sK[n][qq * 8 + u] = acc[u];
        } else {
#pragma unroll
            for (int u = 0; u < 8; ++u) sV[n][qq * 8 + u] = acc[u];
        }
    }
    __syncthreads();

    float qr[32];
#pragma unroll
    for (int j = 0; j < 8; ++j) {
        float4 f = *(const float4*)&sQ[n][j * 4];
        qr[j * 4 + 0] = f.x; qr[j * 4 + 1] = f.y;
        qr[j * 4 + 2] = f.z; qr[j * 4 + 3] = f.w;
    }
    const float scale = 0.17677669529663687f;
    float sc[16];
#pragma unroll
    for (int i = 0; i < 16; ++i) {
        int m = qq * 16 + i;
        float d = 0.f;
#pragma unroll
        for (int j = 0; j < 8; ++j) {
            float4 f = *(const float4*)&sK[m][j * 4];
            d += qr[j * 4 + 0] * f.x + qr[j * 4 + 1] * f.y +
                 qr[j * 4 + 2] * f.z + qr[j * 4 + 3] * f.w;
        }
        sc[i] = d * scale;
    }
    float mx = sc[0];
#pragma unroll
    for (int i = 1; i < 16; ++i) mx = fmaxf(mx, sc[i]);
    mx = fmaxf(mx, __shfl_xor(mx, 1));
    mx = fmaxf(mx, __shfl_xor(mx, 2));
    float sum = 0.f;
#pragma unroll
    for (int i = 0; i < 16; ++i) { sc[i] = __expf(sc[i] - mx); sum += sc[i]; }
    sum += __shfl_xor(sum, 1);
    sum += __shfl_xor(sum, 2);
    const float inv = 1.0f / sum;
#pragma unroll
    for (int i = 0; i < 16; ++i) sc[i] *= inv;

    {
        size_t wbase = ((((size_t)b * HH + h) * SS + s) * NN + n) * NN + (size_t)qq * 16;
        if constexpr (F32) {
            float* wf = (float*)outv + (size_t)OUT0_ELEMS + wbase;
#pragma unroll
            for (int g = 0; g < 4; ++g) {
                float4 f; f.x = sc[g*4]; f.y = sc[g*4+1]; f.z = sc[g*4+2]; f.w = sc[g*4+3];
                *(float4*)(wf + g * 4) = f;
            }
        } else {
            u16* wo = (u16*)outv + (size_t)OUT0_ELEMS + wbase;
            union { u16 u[16]; uint4 v[2]; } wb;
#pragma unroll
            for (int i = 0; i < 16; ++i) wb.u[i] = f2bf(sc[i]);
            *(uint4*)wo = wb.v[0];
            *(uint4*)(wo + 8) = wb.v[1];
        }
    }

    float ao[32];
#pragma unroll
    for (int d = 0; d < 32; ++d) ao[d] = 0.f;
#pragma unroll
    for (int i = 0; i < 16; ++i) {
        int m = qq * 16 + i;
        float w = sc[i];
#pragma unroll
        for (int j = 0; j < 8; ++j) {
            float4 f = *(const float4*)&sV[m][j * 4];
            ao[j * 4 + 0] += w * f.x; ao[j * 4 + 1] += w * f.y;
            ao[j * 4 + 2] += w * f.z; ao[j * 4 + 3] += w * f.w;
        }
    }
#pragma unroll
    for (int d = 0; d < 32; ++d) {
        ao[d] += __shfl_xor(ao[d], 1);
        ao[d] += __shfl_xor(ao[d], 2);
    }
    {
        size_t abase = ((size_t)bs * NN + n) * DKK + h * DHH + (size_t)qq * 8;
        if constexpr (F32) {
            float* af = (float*)outv + abase;
            float4 f0, f1;
            f0.x = ao[qq*8+0]; f0.y = ao[qq*8+1]; f0.z = ao[qq*8+2]; f0.w = ao[qq*8+3];
            f1.x = ao[qq*8+4]; f1.y = ao[qq*8+5]; f1.z = ao[qq*8+6]; f1.w = ao[qq*8+7];
            *(float4*)af = f0;
            *(float4*)(af + 4) = f1;
        } else {
            union { u16 u[8]; uint4 v; } ob;
#pragma unroll
            for (int u = 0; u < 8; ++u) ob.u[u] = f2bf(ao[qq * 8 + u]);
            *(uint4*)((u16*)outv + abase) = ob.v;
        }
    }
}

template <bool F32>
__global__ __launch_bounds__(256) void k_outproj(
    const void* __restrict__ WOv, const void* __restrict__ bOv,
    void* __restrict__ outv, const int* __restrict__ flag)
{
    if ((flag[0] != 0) != F32) return;

    __shared__ __align__(16) u16 xs[64][264];
    const int t = threadIdx.x;
    const size_t base = (size_t)blockIdx.x * (NN * DKK);

    if constexpr (F32) {
        const float* ag = (const float*)outv + base;
#pragma unroll
        for (int i = 0; i < 16; ++i) {
            int idx = t + (i << 8);
            int r = idx >> 6;
            int c4 = (idx & 63) << 2;
            float4 f = *(const float4*)(ag + (size_t)r * DKK + c4);
            union { u16 u[4]; uint2 v; } pk;
            pk.u[0] = f2bf(f.x); pk.u[1] = f2bf(f.y);
            pk.u[2] = f2bf(f.z); pk.u[3] = f2bf(f.w);
            *(uint2*)&xs[r][c4] = pk.v;
        }
    } else {
        const u16* ag = (const u16*)outv + base;
#pragma unroll
        for (int i = 0; i < 8; ++i) {
            int idx = t + (i << 8);
            int r = idx >> 5;
            int c = (idx & 31) << 3;
            *(uint4*)&xs[r][c] = ((const uint4*)ag)[idx];
        }
    }
    __syncthreads();

    const int n = t >> 2;
    const int jj = t & 3;
    for (int cg = 0; cg < 8; ++cg) {
        const int colbase = cg * 32 + jj * 8;
        float acc[8];
        if constexpr (F32) {
            const float* bb = (const float*)bOv;
#pragma unroll
            for (int u = 0; u < 8; ++u) acc[u] = bb[colbase + u];
        } else {
            const u16* bb = (const u16*)bOv;
#pragma unroll
            for (int u = 0; u < 8; ++u) acc[u] = bf2f(bb[colbase + u]);
        }
        const u16* xr = xs[n];
        if constexpr (F32) {
            const float* W = (const float*)WOv + colbase;
#pragma unroll 4
            for (int kk = 0; kk < DKK; ++kk) {
                float x = bf2f(xr[kk]);
                float4 w0 = *(const float4*)(W + (size_t)kk * DKK);
                float4 w1 = *(const float4*)(W + (size_t)kk * DKK + 4);
                acc[0] += x * w0.x; acc[1] += x * w0.y;
                acc[2] += x * w0.z; acc[3] += x * w0.w;
                acc[4] += x * w1.x; acc[5] += x * w1.y;
                acc[6] += x * w1.z; acc[7] += x * w1.w;
            }
        } else {
            const u16* W = (const u16*)WOv + colbase;
#pragma unroll 4
            for (int kk = 0; kk < DKK; ++kk) {
                float x = bf2f(xr[kk]);
                uint4 wv = *(const uint4*)(W + (size_t)kk * DKK);
                const u16* w8 = (const u16*)&wv;
                acc[0] += x * bf2f(w8[0]); acc[1] += x * bf2f(w8[1]);
                acc[2] += x * bf2f(w8[2]); acc[3] += x * bf2f(w8[3]);
                acc[4] += x * bf2f(w8[4]); acc[5] += x * bf2f(w8[5]);
                acc[6] += x * bf2f(w8[6]); acc[7] += x * bf2f(w8[7]);
            }
        }
        if constexpr (F32) {
            float* og = (float*)outv + base + (size_t)n * DKK + colbase;
            float4 f0, f1;
            f0.x = acc[0]; f0.y = acc[1]; f0.z = acc[2]; f0.w = acc[3];
            f1.x = acc[4]; f1.y = acc[5]; f1.z = acc[6]; f1.w = acc[7];
            *(float4*)og = f0;
            *(float4*)(og + 4) = f1;
        } else {
            union { u16 u[8]; uint4 v; } ob;
#pragma unroll
            for (int u = 0; u < 8; ++u) ob.u[u] = f2bf(acc[u]);
            *(uint4*)((u16*)outv + base + (size_t)n * DKK + colbase) = ob.v;
        }
    }
}

extern "C" void kernel_launch(void* const* d_in, const int* in_sizes, int n_in,
                              void* d_out, int out_size, void* d_ws, size_t ws_size,
                              hipStream_t stream) {
    (void)in_sizes; (void)n_in; (void)out_size;
    int* flag = (int*)d_ws;

    k_detect<<<1, 256, 0, stream>>>((const u16*)d_in[3], flag);

    if (ws_size >= WS_WT) {
        k_wt<<<64, 256, 0, stream>>>(d_in[3], d_in[5], d_in[7], d_in[9], d_ws, flag);

        k_attn_mfma<false><<<BB * SS * HH, 256, 0, stream>>>(
            d_in[0], d_in[1], d_in[2], d_in[4], d_in[6], d_in[8],
            d_ws, d_out, flag);
        k_attn_mfma<true><<<BB * SS * HH, 256, 0, stream>>>(
            d_in[0], d_in[1], d_in[2], d_in[4], d_in[6], d_in[8],
            d_ws, d_out, flag);

        k_outproj_mfma<false><<<BB * SS, 256, 0, stream>>>(d_ws, d_in[10], d_out, flag);
        k_outproj_mfma<true><<<BB * SS, 256, 0, stream>>>(d_ws, d_in[10], d_out, flag);
    } else {
        k_attn<false><<<BB * SS * HH, 256, 0, stream>>>(
            d_in[0], d_in[1], d_in[2], d_in[3], d_in[4], d_in[5], d_in[6],
            d_in[7], d_in[8], d_out, flag);
        k_attn<true><<<BB * SS * HH, 256, 0, stream>>>(
            d_in[0], d_in[1], d_in[2], d_in[3], d_in[4], d_in[5], d_in[6],
            d_in[7], d_in[8], d_out, flag);

        k_outproj<false><<<BB * SS, 256, 0, stream>>>(d_in[9], d_in[10], d_out, flag);
        k_outproj<true><<<BB * SS, 256, 0, stream>>>(d_in[9], d_in[10], d_out, flag);
    }
}

// Round 7
// 949.767 us; speedup vs baseline: 1.0126x; 1.0026x over previous
//
#include <hip/hip_runtime.h>

#define BB 8
#define SS 128
#define NN 64
#define DKK 256
#define HH 8
#define DHH 32
#define OUT0_ELEMS 16777216   // B*S*N*DK
// weights elems: B*H*S*N*N = 33554432

typedef unsigned short u16;
typedef __attribute__((ext_vector_type(8))) short short8;   // 8 bf16 (4 VGPRs)
typedef __attribute__((ext_vector_type(4))) float f32x4;    // MFMA C/D frag

#define WS_WT 1049088ull   // flag + WT hi/lo

__device__ __forceinline__ float bf2f(u16 u) {
    union { unsigned int ui; float f; } c;
    c.ui = ((unsigned int)u) << 16;
    return c.f;
}
// Bit-trick RNE f32->bf16 (output packing paths).
__device__ __forceinline__ u16 f2bf(float f) {
    union { float f; unsigned int u; } c;
    c.f = f;
    unsigned int u = c.u;
    return (u16)((u + 0x7fffu + ((u >> 16) & 1u)) >> 16);
}
// Compiler-visible RNE conversion (lowers to v_cvt_pk_bf16_f32 when paired).
__device__ __forceinline__ u16 f2bf_hw(float f) {
    union { __bf16 b; u16 u; } c;
    c.b = (__bf16)f;
    return c.u;
}
// hi/lo split of 8 f32 lanes into two bf16x8 fragments (RNE, exact residual).
__device__ __forceinline__ void split8(float4 a0, float4 a1, short8& hi, short8& lo) {
    float x8[8] = {a0.x, a0.y, a0.z, a0.w, a1.x, a1.y, a1.z, a1.w};
#pragma unroll
    for (int j = 0; j < 8; ++j) {
        u16 hh = f2bf_hw(x8[j]);
        hi[j] = (short)hh;
        lo[j] = (short)f2bf_hw(x8[j] - bf2f(hh));
    }
}

// Skewed row offset for 36-float rows (+4 floats every 16 rows): breaks the
// 576-dword (bank-identical) aliasing between qq row-groups in scores/PV.
__device__ __forceinline__ int ro(int m) { return m * 36 + ((m >> 4) << 2); }

// Detect input dtype: flag=1 => f32 mode.
__global__ void k_detect(const u16* __restrict__ w, int* __restrict__ flag) {
    __shared__ int cnt;
    if (threadIdx.x == 0) cnt = 0;
    __syncthreads();
    int bad = 0;
    for (int i = threadIdx.x; i < 8192; i += 256) {
        float v = bf2f(w[i]);
        if (!(fabsf(v) <= 1e3f)) bad++;
    }
    if (bad) atomicAdd(&cnt, bad);
    __syncthreads();
    if (threadIdx.x == 0) flag[0] = (cnt > 64) ? 1 : 0;
}

// Transpose the 4 weight matrices into ws as bf16 WT[n][k] (hi always; lo
// residual only in f32 mode). Coalesced via 64x64 LDS tile transpose.
// grid: 4 matrices x 16 tiles = 64 blocks, 256 threads.
__global__ __launch_bounds__(256) void k_wt(
    const void* __restrict__ w0, const void* __restrict__ w1,
    const void* __restrict__ w2, const void* __restrict__ w3,
    void* __restrict__ ws, const int* __restrict__ flag) {
    const int f32m = flag[0];
    const int p = blockIdx.x >> 4;
    const int tile = blockIdx.x & 15;
    const int ko = (tile >> 2) << 6;
    const int no = (tile & 3) << 6;
    const void* W = (p == 0) ? w0 : (p == 1) ? w1 : (p == 2) ? w2 : w3;
    u16* hi = (u16*)((char*)ws + 512) + (size_t)p * 65536;
    u16* lo = hi + 4 * 65536;

    __shared__ __align__(16) char tbuf[64 * 65 * 4];
    const int t = threadIdx.x;
    const int tq = t >> 6;        // 0..3
    const int tc = t & 63;        // 0..63

    if (f32m) {
        float (*tl)[65] = (float (*)[65])tbuf;
#pragma unroll
        for (int rr = 0; rr < 16; ++rr) {
            int kk = tq + (rr << 2);
            tl[kk][tc] = ((const float*)W)[(size_t)(ko + kk) * 256 + no + tc];
        }
        __syncthreads();
#pragma unroll
        for (int rr = 0; rr < 16; ++rr) {
            int nn = tq + (rr << 2);
            float x = tl[tc][nn];
            u16 h = f2bf(x);
            size_t o = (size_t)(no + nn) * 256 + ko + tc;
            hi[o] = h;
            lo[o] = f2bf(x - bf2f(h));
        }
    } else {
        u16 (*tl)[65] = (u16 (*)[65])tbuf;
#pragma unroll
        for (int rr = 0; rr < 16; ++rr) {
            int kk = tq + (rr << 2);
            tl[kk][tc] = ((const u16*)W)[(size_t)(ko + kk) * 256 + no + tc];
        }
        __syncthreads();
#pragma unroll
        for (int rr = 0; rr < 16; ++rr) {
            int nn = tq + (rr << 2);
            hi[(size_t)(no + nn) * 256 + ko + tc] = tl[tc][nn];
        }
    }
}

// ---------------------------------------------------------------------------
// MFMA attention: one block per (b,s,h), 4 waves; wave w owns agent rows
// [16w,16w+16). XCD swizzle (proven: FETCH 790->103MB): head-blocks of a
// (b,s) share blockIdx%8 -> same XCD L2. Q/K/V projections MERGED into one
// k-loop -> 6 independent MFMA chains, 3x loads in flight per latency round
// (waves were ~90% stalled on serialized vmcnt waits). Per-chain op order
// identical to the split version -> bit-identical output.
// ---------------------------------------------------------------------------
template <bool F32>
__global__ __launch_bounds__(256) void k_attn_mfma(
    const void* __restrict__ qv, const void* __restrict__ kv, const void* __restrict__ vv,
    const void* __restrict__ bQv, const void* __restrict__ bKv, const void* __restrict__ bVv,
    const void* __restrict__ ws, void* __restrict__ outv, const int* __restrict__ flag)
{
    if ((flag[0] != 0) != F32) return;

    __shared__ float sQ[2320], sK[2320], sV[2320];

    const int t = threadIdx.x;
    const int wv_ = t >> 6;          // wave id = M-tile
    const int lane = t & 63;
    const int li = lane & 15;        // A row-in-tile / B,C col-in-tile
    const int lg = lane >> 4;        // K-subgroup / C row-group
    // XCD swizzle: lid = (bs%8) + 8*h + 64*(bs/8)  (bijective on [0,8192))
    const int lid = blockIdx.x;
    const int bs = (lid & 7) + ((lid >> 6) << 3);
    const int h = (lid >> 3) & 7;
    const int b = bs >> 7;
    const int s = bs & 127;

    const u16* wt = (const u16*)((const char*)ws + 512);
    const size_t arow = ((size_t)bs * 64 + wv_ * 16 + li) * 256;
    // B fragment base pointers: col li (b0) and col li+16 (b1) of head h.
    const u16* b0p = wt + (size_t)(h * 32 + li) * 256;
    const u16* b1p = b0p + 4096;     // +16 cols

    // Accumulators: 2 chains per tensor, bias-initialized.
    f32x4 cQ0, cQ1, cK0, cK1, cV0, cV1;
    {
        float vq0, vq1, vk0, vk1, vv0, vv1;
        if constexpr (F32) {
            vq0 = ((const float*)bQv)[h * 32 + li];
            vq1 = ((const float*)bQv)[h * 32 + 16 + li];
            vk0 = ((const float*)bKv)[h * 32 + li];
            vk1 = ((const float*)bKv)[h * 32 + 16 + li];
            vv0 = ((const float*)bVv)[h * 32 + li];
            vv1 = ((const float*)bVv)[h * 32 + 16 + li];
        } else {
            vq0 = bf2f(((const u16*)bQv)[h * 32 + li]);
            vq1 = bf2f(((const u16*)bQv)[h * 32 + 16 + li]);
            vk0 = bf2f(((const u16*)bKv)[h * 32 + li]);
            vk1 = bf2f(((const u16*)bKv)[h * 32 + 16 + li]);
            vv0 = bf2f(((const u16*)bVv)[h * 32 + li]);
            vv1 = bf2f(((const u16*)bVv)[h * 32 + 16 + li]);
        }
        cQ0 = f32x4{vq0, vq0, vq0, vq0}; cQ1 = f32x4{vq1, vq1, vq1, vq1};
        cK0 = f32x4{vk0, vk0, vk0, vk0}; cK1 = f32x4{vk1, vk1, vk1, vk1};
        cV0 = f32x4{vv0, vv0, vv0, vv0}; cV1 = f32x4{vv1, vv1, vv1, vv1};
    }

    if constexpr (F32) {
        const float* xq = (const float*)qv + arow + lg * 8;
        const float* xk = (const float*)kv + arow + lg * 8;
        const float* xv = (const float*)vv + arow + lg * 8;
#pragma unroll
        for (int ks = 0; ks < 8; ++ks) {
            const int kof = ks * 32 + lg * 8;
            // A loads: 6 independent float4 pairs (3 tensors) — all in flight
            float4 q0 = *(const float4*)(xq + ks * 32);
            float4 q1 = *(const float4*)(xq + ks * 32 + 4);
            float4 k0 = *(const float4*)(xk + ks * 32);
            float4 k1 = *(const float4*)(xk + ks * 32 + 4);
            float4 v0 = *(const float4*)(xv + ks * 32);
            float4 v1 = *(const float4*)(xv + ks * 32 + 4);
            // B loads: 12 independent short8 (3 tensors x 2 cols x hi/lo)
            short8 bqh0 = *(const short8*)(b0p + kof);
            short8 bqh1 = *(const short8*)(b1p + kof);
            short8 bql0 = *(const short8*)(b0p + 262144 + kof);
            short8 bql1 = *(const short8*)(b1p + 262144 + kof);
            short8 bkh0 = *(const short8*)(b0p + 65536 + kof);
            short8 bkh1 = *(const short8*)(b1p + 65536 + kof);
            short8 bkl0 = *(const short8*)(b0p + 327680 + kof);
            short8 bkl1 = *(const short8*)(b1p + 327680 + kof);
            short8 bvh0 = *(const short8*)(b0p + 131072 + kof);
            short8 bvh1 = *(const short8*)(b1p + 131072 + kof);
            short8 bvl0 = *(const short8*)(b0p + 393216 + kof);
            short8 bvl1 = *(const short8*)(b1p + 393216 + kof);
            short8 aqh, aql, akh, akl, avh, avl;
            split8(q0, q1, aqh, aql);
            split8(k0, k1, akh, akl);
            split8(v0, v1, avh, avl);
            // 18 MFMAs, 6 independent chains (per-chain order = split version)
            cQ0 = __builtin_amdgcn_mfma_f32_16x16x32_bf16(aqh, bqh0, cQ0, 0, 0, 0);
            cK0 = __builtin_amdgcn_mfma_f32_16x16x32_bf16(akh, bkh0, cK0, 0, 0, 0);
            cV0 = __builtin_amdgcn_mfma_f32_16x16x32_bf16(avh, bvh0, cV0, 0, 0, 0);
            cQ1 = __builtin_amdgcn_mfma_f32_16x16x32_bf16(aqh, bqh1, cQ1, 0, 0, 0);
            cK1 = __builtin_amdgcn_mfma_f32_16x16x32_bf16(akh, bkh1, cK1, 0, 0, 0);
            cV1 = __builtin_amdgcn_mfma_f32_16x16x32_bf16(avh, bvh1, cV1, 0, 0, 0);
            cQ0 = __builtin_amdgcn_mfma_f32_16x16x32_bf16(aqh, bql0, cQ0, 0, 0, 0);
            cK0 = __builtin_amdgcn_mfma_f32_16x16x32_bf16(akh, bkl0, cK0, 0, 0, 0);
            cV0 = __builtin_amdgcn_mfma_f32_16x16x32_bf16(avh, bvl0, cV0, 0, 0, 0);
            cQ0 = __builtin_amdgcn_mfma_f32_16x16x32_bf16(aql, bqh0, cQ0, 0, 0, 0);
            cK0 = __builtin_amdgcn_mfma_f32_16x16x32_bf16(akl, bkh0, cK0, 0, 0, 0);
            cV0 = __builtin_amdgcn_mfma_f32_16x16x32_bf16(avl, bvh0, cV0, 0, 0, 0);
            cQ1 = __builtin_amdgcn_mfma_f32_16x16x32_bf16(aqh, bql1, cQ1, 0, 0, 0);
            cK1 = __builtin_amdgcn_mfma_f32_16x16x32_bf16(akh, bkl1, cK1, 0, 0, 0);
            cV1 = __builtin_amdgcn_mfma_f32_16x16x32_bf16(avh, bvl1, cV1, 0, 0, 0);
            cQ1 = __builtin_amdgcn_mfma_f32_16x16x32_bf16(aql, bqh1, cQ1, 0, 0, 0);
            cK1 = __builtin_amdgcn_mfma_f32_16x16x32_bf16(akl, bkh1, cK1, 0, 0, 0);
            cV1 = __builtin_amdgcn_mfma_f32_16x16x32_bf16(avl, bvh1, cV1, 0, 0, 0);
        }
    } else {
        const u16* xq = (const u16*)qv + arow;
        const u16* xk = (const u16*)kv + arow;
        const u16* xv = (const u16*)vv + arow;
#pragma unroll
        for (int ks = 0; ks < 8; ++ks) {
            const int kof = ks * 32 + lg * 8;
            short8 aq = *(const short8*)(xq + kof);
            short8 ak = *(const short8*)(xk + kof);
            short8 av = *(const short8*)(xv + kof);
            short8 bq0 = *(const short8*)(b0p + kof);
            short8 bq1 = *(const short8*)(b1p + kof);
            short8 bk0 = *(const short8*)(b0p + 65536 + kof);
            short8 bk1 = *(const short8*)(b1p + 65536 + kof);
            short8 bv0 = *(const short8*)(b0p + 131072 + kof);
            short8 bv1 = *(const short8*)(b1p + 131072 + kof);
            cQ0 = __builtin_amdgcn_mfma_f32_16x16x32_bf16(aq, bq0, cQ0, 0, 0, 0);
            cK0 = __builtin_amdgcn_mfma_f32_16x16x32_bf16(ak, bk0, cK0, 0, 0, 0);
            cV0 = __builtin_amdgcn_mfma_f32_16x16x32_bf16(av, bv0, cV0, 0, 0, 0);
            cQ1 = __builtin_amdgcn_mfma_f32_16x16x32_bf16(aq, bq1, cQ1, 0, 0, 0);
            cK1 = __builtin_amdgcn_mfma_f32_16x16x32_bf16(ak, bk1, cK1, 0, 0, 0);
            cV1 = __builtin_amdgcn_mfma_f32_16x16x32_bf16(av, bv1, cV1, 0, 0, 0);
        }
    }

    // C-frags -> LDS (skewed layout)
    {
        const int row0 = wv_ * 16 + lg * 4;
#pragma unroll
        for (int r = 0; r < 4; ++r) {
            int o = ro(row0 + r);
            sQ[o + li] = cQ0[r]; sQ[o + 16 + li] = cQ1[r];
            sK[o + li] = cK0[r]; sK[o + 16 + li] = cK1[r];
            sV[o + li] = cV0[r]; sV[o + 16 + li] = cV1[r];
        }
    }
    __syncthreads();

    // ---- scores + softmax; thread (n,qq) owns m = qq*16 .. qq*16+15 ----
    const int n = t >> 2;
    const int qq = t & 3;
    float qr[32];
#pragma unroll
    for (int j = 0; j < 8; ++j) {
        float4 f = *(const float4*)&sQ[ro(n) + j * 4];
        qr[j * 4 + 0] = f.x; qr[j * 4 + 1] = f.y;
        qr[j * 4 + 2] = f.z; qr[j * 4 + 3] = f.w;
    }
    const float scale = 0.17677669529663687f;  // 1/sqrt(32)
    float sc[16];
#pragma unroll
    for (int i = 0; i < 16; ++i) {
        int m = qq * 16 + i;
        float d = 0.f;
        const float* kr = &sK[ro(m)];
#pragma unroll
        for (int j = 0; j < 8; ++j) {
            float4 f = *(const float4*)(kr + j * 4);
            d += qr[j * 4 + 0] * f.x + qr[j * 4 + 1] * f.y +
                 qr[j * 4 + 2] * f.z + qr[j * 4 + 3] * f.w;
        }
        sc[i] = d * scale;
    }
    float mx = sc[0];
#pragma unroll
    for (int i = 1; i < 16; ++i) mx = fmaxf(mx, sc[i]);
    mx = fmaxf(mx, __shfl_xor(mx, 1));
    mx = fmaxf(mx, __shfl_xor(mx, 2));
    float sum = 0.f;
#pragma unroll
    for (int i = 0; i < 16; ++i) { sc[i] = __expf(sc[i] - mx); sum += sc[i]; }
    sum += __shfl_xor(sum, 1);
    sum += __shfl_xor(sum, 2);
    const float inv = 1.0f / sum;
#pragma unroll
    for (int i = 0; i < 16; ++i) sc[i] *= inv;

    // weights out
    {
        size_t wbase = ((((size_t)b * HH + h) * SS + s) * NN + n) * NN + (size_t)qq * 16;
        if constexpr (F32) {
            float* wf = (float*)outv + (size_t)OUT0_ELEMS + wbase;
#pragma unroll
            for (int g = 0; g < 4; ++g) {
                float4 f; f.x = sc[g*4]; f.y = sc[g*4+1]; f.z = sc[g*4+2]; f.w = sc[g*4+3];
                *(float4*)(wf + g * 4) = f;
            }
        } else {
            u16* wo = (u16*)outv + (size_t)OUT0_ELEMS + wbase;
            union { u16 u[16]; uint4 v[2]; } wb;
#pragma unroll
            for (int i = 0; i < 16; ++i) wb.u[i] = f2bf(sc[i]);
            *(uint4*)wo = wb.v[0];
            *(uint4*)(wo + 8) = wb.v[1];
        }
    }

    // ---- P @ V ----
    float ao[32];
#pragma unroll
    for (int d = 0; d < 32; ++d) ao[d] = 0.f;
#pragma unroll
    for (int i = 0; i < 16; ++i) {
        int m = qq * 16 + i;
        float w = sc[i];
        const float* vr = &sV[ro(m)];
#pragma unroll
        for (int j = 0; j < 8; ++j) {
            float4 f = *(const float4*)(vr + j * 4);
            ao[j * 4 + 0] += w * f.x; ao[j * 4 + 1] += w * f.y;
            ao[j * 4 + 2] += w * f.z; ao[j * 4 + 3] += w * f.w;
        }
    }
#pragma unroll
    for (int d = 0; d < 32; ++d) {
        ao[d] += __shfl_xor(ao[d], 1);
        ao[d] += __shfl_xor(ao[d], 2);
    }
    {
        size_t abase = ((size_t)bs * NN + n) * DKK + h * DHH + (size_t)qq * 8;
        if constexpr (F32) {
            float* af = (float*)outv + abase;
            float4 f0, f1;
            f0.x = ao[qq*8+0]; f0.y = ao[qq*8+1]; f0.z = ao[qq*8+2]; f0.w = ao[qq*8+3];
            f1.x = ao[qq*8+4]; f1.y = ao[qq*8+5]; f1.z = ao[qq*8+6]; f1.w = ao[qq*8+7];
            *(float4*)af = f0;
            *(float4*)(af + 4) = f1;
        } else {
            union { u16 u[8]; uint4 v; } ob;
#pragma unroll
            for (int u = 0; u < 8; ++u) ob.u[u] = f2bf(ao[qq * 8 + u]);
            *(uint4*)((u16*)outv + abase) = ob.v;
        }
    }
}

// ---------------------------------------------------------------------------
// MFMA out-projection: one block per (b,s), 4 waves. attn rows pre-loaded to
// registers (bf16, matching old rounding) so the in-place write is hazard-free.
// ---------------------------------------------------------------------------
template <bool F32>
__global__ __launch_bounds__(256) void k_outproj_mfma(
    const void* __restrict__ ws, const void* __restrict__ bOv,
    void* __restrict__ outv, const int* __restrict__ flag)
{
    if ((flag[0] != 0) != F32) return;

    const int t = threadIdx.x;
    const int wv_ = t >> 6, lane = t & 63, li = lane & 15, lg = lane >> 4;
    const size_t base = (size_t)blockIdx.x * (NN * DKK);
    const u16* wt = (const u16*)((const char*)ws + 512) + (size_t)3 * 65536;
    const u16* wtl = wt + 4 * 65536;

    short8 a[8];
    const size_t arow = base + (size_t)(wv_ * 16 + li) * 256;
    if constexpr (F32) {
        float4 X0[8], X1[8];
        const float* xp0 = (const float*)outv + arow + lg * 8;
#pragma unroll
        for (int ks = 0; ks < 8; ++ks) {
            X0[ks] = *(const float4*)(xp0 + ks * 32);
            X1[ks] = *(const float4*)(xp0 + ks * 32 + 4);
        }
#pragma unroll
        for (int ks = 0; ks < 8; ++ks) {
            float x8[8] = {X0[ks].x, X0[ks].y, X0[ks].z, X0[ks].w,
                           X1[ks].x, X1[ks].y, X1[ks].z, X1[ks].w};
#pragma unroll
            for (int j = 0; j < 8; ++j) a[ks][j] = (short)f2bf_hw(x8[j]);
        }
    } else {
#pragma unroll
        for (int ks = 0; ks < 8; ++ks) {
            const int kof = ks * 32 + lg * 8;
            a[ks] = *(const short8*)((const u16*)outv + arow + kof);
        }
    }

    for (int nt = 0; nt < 16; ++nt) {
        const int col = nt * 16 + li;
        float bv;
        if constexpr (F32) bv = ((const float*)bOv)[col];
        else               bv = bf2f(((const u16*)bOv)[col]);
        f32x4 c = {bv, bv, bv, bv};
#pragma unroll
        for (int ks = 0; ks < 8; ++ks) {
            const int kof = ks * 32 + lg * 8;
            short8 bh = *(const short8*)(wt + (size_t)col * 256 + kof);
            c = __builtin_amdgcn_mfma_f32_16x16x32_bf16(a[ks], bh, c, 0, 0, 0);
            if constexpr (F32) {
                short8 bl = *(const short8*)(wtl + (size_t)col * 256 + kof);
                c = __builtin_amdgcn_mfma_f32_16x16x32_bf16(a[ks], bl, c, 0, 0, 0);
            }
        }
#pragma unroll
        for (int r = 0; r < 4; ++r) {
            size_t off = base + (size_t)(wv_ * 16 + lg * 4 + r) * 256 + col;
            if constexpr (F32) ((float*)outv)[off] = c[r];
            else               ((u16*)outv)[off] = f2bf(c[r]);
        }
    }
}

// ===========================================================================
// Fallback path (original VALU kernels) — used only if workspace is tiny.
// ===========================================================================
template <bool F32>
__global__ __launch_bounds__(256) void k_attn(
    const void* __restrict__ qv, const void* __restrict__ kv, const void* __restrict__ vv,
    const void* __restrict__ WQv, const void* __restrict__ bQv,
    const void* __restrict__ WKv, const void* __restrict__ bKv,
    const void* __restrict__ WVv, const void* __restrict__ bVv,
    void* __restrict__ outv, const int* __restrict__ flag)
{
    if ((flag[0] != 0) != F32) return;

    __shared__ __align__(16) char smem[60416];
    float (*sQ)[36] = (float (*)[36])(smem + 33792);
    float (*sK)[36] = (float (*)[36])(smem + 33792 + 9216);
    float (*sV)[32] = (float (*)[32])(smem + 33792 + 18432);

    const int t  = threadIdx.x;
    const int bs = blockIdx.x >> 3;
    const int h  = blockIdx.x & 7;
    const int b  = bs >> 7;
    const int s  = bs & 127;
    const int n  = t >> 2;
    const int qq = t & 3;
    const int colbase = h * DHH + qq * 8;
    const size_t xoff = (size_t)bs * (NN * DKK);

    for (int p = 0; p < 3; ++p) {
        const void* Xp = (p == 0) ? qv : (p == 1) ? kv : vv;
        const void* Wp_ = (p == 0) ? WQv : (p == 1) ? WKv : WVv;
        const void* bp_ = (p == 0) ? bQv : (p == 1) ? bKv : bVv;
        float acc[8];

        if constexpr (F32) {
            const float* bb = (const float*)bp_;
#pragma unroll
            for (int u = 0; u < 8; ++u) acc[u] = bb[colbase + u];
            const float* X = (const float*)Xp + xoff;
            const float* W = (const float*)Wp_ + colbase;
            float (*xsf)[132] = (float (*)[132])smem;
            for (int half = 0; half < 2; ++half) {
                __syncthreads();
#pragma unroll
                for (int i = 0; i < 8; ++i) {
                    int idx = t + (i << 8);
                    int r = idx >> 5;
                    int c4 = (idx & 31) << 2;
                    *(float4*)&xsf[r][c4] =
                        *(const float4*)(X + (size_t)r * DKK + (half << 7) + c4);
                }
                __syncthreads();
#pragma unroll 4
                for (int kk2 = 0; kk2 < 128; ++kk2) {
                    int kk = (half << 7) + kk2;
                    float x = xsf[n][kk2];
                    float4 w0 = *(const float4*)(W + (size_t)kk * DKK);
                    float4 w1 = *(const float4*)(W + (size_t)kk * DKK + 4);
                    acc[0] += x * w0.x; acc[1] += x * w0.y;
                    acc[2] += x * w0.z; acc[3] += x * w0.w;
                    acc[4] += x * w1.x; acc[5] += x * w1.y;
                    acc[6] += x * w1.z; acc[7] += x * w1.w;
                }
            }
        } else {
            const u16* bb = (const u16*)bp_;
#pragma unroll
            for (int u = 0; u < 8; ++u) acc[u] = bf2f(bb[colbase + u]);
            const u16* X = (const u16*)Xp + xoff;
            const u16* W = (const u16*)Wp_ + colbase;
            u16 (*xs)[264] = (u16 (*)[264])smem;
            __syncthreads();
#pragma unroll
            for (int i = 0; i < 8; ++i) {
                int idx = t + (i << 8);
                int r = idx >> 5;
                int c = (idx & 31) << 3;
                *(uint4*)&xs[r][c] = ((const uint4*)X)[idx];
            }
            __syncthreads();
#pragma unroll 4
            for (int kk = 0; kk < DKK; ++kk) {
                float x = bf2f(xs[n][kk]);
                uint4 wv = *(const uint4*)(W + (size_t)kk * DKK);
                const u16* w8 = (const u16*)&wv;
                acc[0] += x * bf2f(w8[0]); acc[1] += x * bf2f(w8[1]);
                acc[2] += x * bf2f(w8[2]); acc[3] += x * bf2f(w8[3]);
                acc[4] += x * bf2f(w8[4]); acc[5] += x * bf2f(w8[5]);
                acc[6] += x * bf2f(w8[6]); acc[7] += x * bf2f(w8[7]);
            }
        }

        if (p == 0) {
#pragma unroll
            for (int u = 0; u < 8; ++u) sQ[n][qq * 8 + u] = acc[u];
        } else if (p == 1) {
#pragma unroll
            for (int u = 0; u < 8; ++u) sK[n][qq * 8 + u] = acc[u];
        } else {
#pragma unroll
            for (int u = 0; u < 8; ++u) sV[n][qq * 8 + u] = acc[u];
        }
    }
    __syncthreads();

    float qr[32];
#pragma unroll
    for (int j = 0; j < 8; ++j) {
        float4 f = *(const float4*)&sQ[n][j * 4];
        qr[j * 4 + 0] = f.x; qr[j * 4 + 1] = f.y;
        qr[j * 4 + 2] = f.z; qr[j * 4 + 3] = f.w;
    }
    const float scale = 0.17677669529663687f;
    float sc[16];
#pragma unroll
    for (int i = 0; i < 16; ++i) {
        int m = qq * 16 + i;
        float d = 0.f;
#pragma unroll
        for (int j = 0; j < 8; ++j) {
            float4 f = *(const float4*)&sK[m][j * 4];
            d += qr[j * 4 + 0] * f.x + qr[j * 4 + 1] * f.y +
                 qr[j * 4 + 2] * f.z + qr[j * 4 + 3] * f.w;
        }
        sc[i] = d * scale;
    }
    float mx = sc[0];
#pragma unroll
    for (int i = 1; i < 16; ++i) mx = fmaxf(mx, sc[i]);
    mx = fmaxf(mx, __shfl_xor(mx, 1));
    mx = fmaxf(mx, __shfl_xor(mx, 2));
    float sum = 0.f;
#pragma unroll
    for (int i = 0; i < 16; ++i) { sc[i] = __expf(sc[i] - mx); sum += sc[i]; }
    sum += __shfl_xor(sum, 1);
    sum += __shfl_xor(sum, 2);
    const float inv = 1.0f / sum;
#pragma unroll
    for (int i = 0; i < 16; ++i) sc[i] *= inv;

    {
        size_t wbase = ((((size_t)b * HH + h) * SS + s) * NN + n) * NN + (size_t)qq * 16;
        if constexpr (F32) {
            float* wf = (float*)outv + (size_t)OUT0_ELEMS + wbase;
#pragma unroll
            for (int g = 0; g < 4; ++g) {
                float4 f; f.x = sc[g*4]; f.y = sc[g*4+1]; f.z = sc[g*4+2]; f.w = sc[g*4+3];
                *(float4*)(wf + g * 4) = f;
            }
        } else {
            u16* wo = (u16*)outv + (size_t)OUT0_ELEMS + wbase;
            union { u16 u[16]; uint4 v[2]; } wb;
#pragma unroll
            for (int i = 0; i < 16; ++i) wb.u[i] = f2bf(sc[i]);
            *(uint4*)wo = wb.v[0];
            *(uint4*)(wo + 8) = wb.v[1];
        }
    }

    float ao[32];
#pragma unroll
    for (int d = 0; d < 32; ++d) ao[d] = 0.f;
#pragma unroll
    for (int i = 0; i < 16; ++i) {
        int m = qq * 16 + i;
        float w = sc[i];
#pragma unroll
        for (int j = 0; j < 8; ++j) {
            float4 f = *(const float4*)&sV[m][j * 4];
            ao[j * 4 + 0] += w * f.x; ao[j * 4 + 1] += w * f.y;
            ao[j * 4 + 2] += w * f.z; ao[j * 4 + 3] += w * f.w;
        }
    }
#pragma unroll
    for (int d = 0; d < 32; ++d) {
        ao[d] += __shfl_xor(ao[d], 1);
        ao[d] += __shfl_xor(ao[d], 2);
    }
    {
        size_t abase = ((size_t)bs * NN + n) * DKK + h * DHH + (size_t)qq * 8;
        if constexpr (F32) {
            float* af = (float*)outv + abase;
            float4 f0, f1;
            f0.x = ao[qq*8+0]; f0.y = ao[qq*8+1]; f0.z = ao[qq*8+2]; f0.w = ao[qq*8+3];
            f1.x = ao[qq*8+4]; f1.y = ao[qq*8+5]; f1.z = ao[qq*8+6]; f1.w = ao[qq*8+7];
            *(float4*)af = f0;
            *(float4*)(af + 4) = f1;
        } else {
            union { u16 u[8]; uint4 v; } ob;
#pragma unroll
            for (int u = 0; u < 8; ++u) ob.u[u] = f2bf(ao[qq * 8 + u]);
            *(uint4*)((u16*)outv + abase) = ob.v;
        }
    }
}

template <bool F32>
__global__ __launch_bounds__(256) void k_outproj(
    const void* __restrict__ WOv, const void* __restrict__ bOv,
    void* __restrict__ outv, const int* __restrict__ flag)
{
    if ((flag[0] != 0) != F32) return;

    __shared__ __align__(16) u16 xs[64][264];
    const int t = threadIdx.x;
    const size_t base = (size_t)blockIdx.x * (NN * DKK);

    if constexpr (F32) {
        const float* ag = (const float*)outv + base;
#pragma unroll
        for (int i = 0; i < 16; ++i) {
            int idx = t + (i << 8);
            int r = idx >> 6;
            int c4 = (idx & 63) << 2;
            float4 f = *(const float4*)(ag + (size_t)r * DKK + c4);
            union { u16 u[4]; uint2 v; } pk;
            pk.u[0] = f2bf(f.x); pk.u[1] = f2bf(f.y);
            pk.u[2] = f2bf(f.z); pk.u[3] = f2bf(f.w);
            *(uint2*)&xs[r][c4] = pk.v;
        }
    } else {
        const u16* ag = (const u16*)outv + base;
#pragma unroll
        for (int i = 0; i < 8; ++i) {
            int idx = t + (i << 8);
            int r = idx >> 5;
            int c = (idx & 31) << 3;
            *(uint4*)&xs[r][c] = ((const uint4*)ag)[idx];
        }
    }
    __syncthreads();

    const int n = t >> 2;
    const int jj = t & 3;
    for (int cg = 0; cg < 8; ++cg) {
        const int colbase = cg * 32 + jj * 8;
        float acc[8];
        if constexpr (F32) {
            const float* bb = (const float*)bOv;
#pragma unroll
            for (int u = 0; u < 8; ++u) acc[u] = bb[colbase + u];
        } else {
            const u16* bb = (const u16*)bOv;
#pragma unroll
            for (int u = 0; u < 8; ++u) acc[u] = bf2f(bb[colbase + u]);
        }
        const u16* xr = xs[n];
        if constexpr (F32) {
            const float* W = (const float*)WOv + colbase;
#pragma unroll 4
            for (int kk = 0; kk < DKK; ++kk) {
                float x = bf2f(xr[kk]);
                float4 w0 = *(const float4*)(W + (size_t)kk * DKK);
                float4 w1 = *(const float4*)(W + (size_t)kk * DKK + 4);
                acc[0] += x * w0.x; acc[1] += x * w0.y;
                acc[2] += x * w0.z; acc[3] += x * w0.w;
                acc[4] += x * w1.x; acc[5] += x * w1.y;
                acc[6] += x * w1.z; acc[7] += x * w1.w;
            }
        } else {
            const u16* W = (const u16*)WOv + colbase;
#pragma unroll 4
            for (int kk = 0; kk < DKK; ++kk) {
                float x = bf2f(xr[kk]);
                uint4 wv = *(const uint4*)(W + (size_t)kk * DKK);
                const u16* w8 = (const u16*)&wv;
                acc[0] += x * bf2f(w8[0]); acc[1] += x * bf2f(w8[1]);
                acc[2] += x * bf2f(w8[2]); acc[3] += x * bf2f(w8[3]);
                acc[4] += x * bf2f(w8[4]); acc[5] += x * bf2f(w8[5]);
                acc[6] += x * bf2f(w8[6]); acc[7] += x * bf2f(w8[7]);
            }
        }
        if constexpr (F32) {
            float* og = (float*)outv + base + (size_t)n * DKK + colbase;
            float4 f0, f1;
            f0.x = acc[0]; f0.y = acc[1]; f0.z = acc[2]; f0.w = acc[3];
            f1.x = acc[4]; f1.y = acc[5]; f1.z = acc[6]; f1.w = acc[7];
            *(float4*)og = f0;
            *(float4*)(og + 4) = f1;
        } else {
            union { u16 u[8]; uint4 v; } ob;
#pragma unroll
            for (int u = 0; u < 8; ++u) ob.u[u] = f2bf(acc[u]);
            *(uint4*)((u16*)outv + base + (size_t)n * DKK + colbase) = ob.v;
        }
    }
}

extern "C" void kernel_launch(void* const* d_in, const int* in_sizes, int n_in,
                              void* d_out, int out_size, void* d_ws, size_t ws_size,
                              hipStream_t stream) {
    (void)in_sizes; (void)n_in; (void)out_size;
    int* flag = (int*)d_ws;

    k_detect<<<1, 256, 0, stream>>>((const u16*)d_in[3], flag);

    if (ws_size >= WS_WT) {
        k_wt<<<64, 256, 0, stream>>>(d_in[3], d_in[5], d_in[7], d_in[9], d_ws, flag);

        k_attn_mfma<false><<<BB * SS * HH, 256, 0, stream>>>(
            d_in[0], d_in[1], d_in[2], d_in[4], d_in[6], d_in[8],
            d_ws, d_out, flag);
        k_attn_mfma<true><<<BB * SS * HH, 256, 0, stream>>>(
            d_in[0], d_in[1], d_in[2], d_in[4], d_in[6], d_in[8],
            d_ws, d_out, flag);

        k_outproj_mfma<false><<<BB * SS, 256, 0, stream>>>(d_ws, d_in[10], d_out, flag);
        k_outproj_mfma<true><<<BB * SS, 256, 0, stream>>>(d_ws, d_in[10], d_out, flag);
    } else {
        k_attn<false><<<BB * SS * HH, 256, 0, stream>>>(
            d_in[0], d_in[1], d_in[2], d_in[3], d_in[4], d_in[5], d_in[6],
            d_in[7], d_in[8], d_out, flag);
        k_attn<true><<<BB * SS * HH, 256, 0, stream>>>(
            d_in[0], d_in[1], d_in[2], d_in[3], d_in[4], d_in[5], d_in[6],
            d_in[7], d_in[8], d_out, flag);

        k_outproj<false><<<BB * SS, 256, 0, stream>>>(d_in[9], d_in[10], d_out, flag);
        k_outproj<true><<<BB * SS, 256, 0, stream>>>(d_in[9], d_in[10], d_out, flag);
    }
}